// Round 2
// baseline (9.718 us; speedup 1.0000x reference)
//
#include <hip/hip_runtime.h>
#include <hip/hip_bf16.h>
#include <math.h>

#define K_SIZE 41

__global__ __launch_bounds__(256)
void FlatDilation1D_kernel(const float* __restrict__ in,
                           const float* __restrict__ scale_p,
                           float* __restrict__ out,
                           int n, int start /* first index of the 41-wide window */) {
    __shared__ float f[K_SIZE];

    const int tid = threadIdx.x;

    if (tid < K_SIZE) {
        const float scale = scale_p[0];
        // f[tid] = max_j ( window[(tid + j) % 41] + h[j] ),
        // h[j] = -((j-20)/scale)^16 via exact repeated squaring (fp32).
        float m = -INFINITY;
        #pragma unroll
        for (int j = 0; j < K_SIZE; ++j) {
            float t   = (float)(j - 20) / scale;
            float t2  = t  * t;
            float t4  = t2 * t2;
            float t8  = t4 * t4;
            float t16 = t8 * t8;

            int idx = tid + j;
            if (idx >= K_SIZE) idx -= K_SIZE;
            m = fmaxf(m, in[start + idx] - t16);
        }
        f[tid] = m;
    }
    __syncthreads();

    // Each thread writes 4 consecutive outputs as one float4.
    const int i0 = (blockIdx.x * blockDim.x + threadIdx.x) * 4;
    if (i0 >= n) return;

    int r = i0 % K_SIZE;           // one magic-mul modulo per thread
    float v0 = f[r];
    if (++r == K_SIZE) r = 0;
    float v1 = f[r];
    if (++r == K_SIZE) r = 0;
    float v2 = f[r];
    if (++r == K_SIZE) r = 0;
    float v3 = f[r];

    if (i0 + 3 < n) {
        *reinterpret_cast<float4*>(out + i0) = make_float4(v0, v1, v2, v3);
    } else {
        out[i0] = v0;
        if (i0 + 1 < n) out[i0 + 1] = v1;
        if (i0 + 2 < n) out[i0 + 2] = v2;
    }
}

extern "C" void kernel_launch(void* const* d_in, const int* in_sizes, int n_in,
                              void* d_out, int out_size, void* d_ws, size_t ws_size,
                              hipStream_t stream) {
    const float* in      = (const float*)d_in[0];
    const float* scale_p = (const float*)d_in[1];
    float* out = (float*)d_out;

    const int n = in_sizes[0];

    // Reference: missing = K - n; left = missing//2 + 2 (Python floor div).
    // For n=8191: missing=-8150 -> left=-4073 -> window = in[4073:4114].
    const int missing = K_SIZE - n;
    int fd = missing / 2;
    if ((missing % 2 != 0) && (missing < 0)) fd -= 1;  // Python floor division
    const int left = fd + 2;
    const int start = -left;

    const int block = 256;
    const int elems_per_block = block * 4;
    const int grid = (n + elems_per_block - 1) / elems_per_block;
    FlatDilation1D_kernel<<<grid, block, 0, stream>>>(in, scale_p, out, n, start);
}

// Round 3
// 9.405 us; speedup vs baseline: 1.0334x; 1.0334x over previous
//
#include <hip/hip_runtime.h>
#include <hip/hip_bf16.h>
#include <math.h>

#define K_SIZE 41

// Single-wave blocks: workgroup(64) == wavefront(64) -> no s_barrier needed,
// __syncthreads() degenerates to an LDS waitcnt. Lanes 0..40 build the
// 41-entry table f[r] = max_j(window[(r+j)%41] + h[j]); then every lane
// writes 4 consecutive outputs out[i] = f[i%41] as one float4.
__global__ __launch_bounds__(64)
void FlatDilation1D_kernel(const float* __restrict__ in,
                           const float* __restrict__ scale_p,
                           float* __restrict__ out,
                           int n, int start /* first index of the 41-wide window */) {
    __shared__ float f[K_SIZE];

    const int tid = threadIdx.x;

    if (tid < K_SIZE) {
        const float scale = scale_p[0];
        float m = -INFINITY;
        #pragma unroll
        for (int j = 0; j < K_SIZE; ++j) {
            // h[j] = -((j-20)/scale)^16, exact repeated squaring in fp32
            float t   = (float)(j - 20) / scale;
            float t2  = t  * t;
            float t4  = t2 * t2;
            float t8  = t4 * t4;
            float t16 = t8 * t8;

            int idx = tid + j;
            if (idx >= K_SIZE) idx -= K_SIZE;
            m = fmaxf(m, in[start + idx] - t16);
        }
        f[tid] = m;
    }
    __syncthreads();   // single wave: compiles to lgkmcnt wait only

    const int i0 = (blockIdx.x * 64 + tid) * 4;
    if (i0 >= n) return;

    int r = i0 % K_SIZE;           // one magic-mul modulo per thread
    float v0 = f[r];
    if (++r == K_SIZE) r = 0;
    float v1 = f[r];
    if (++r == K_SIZE) r = 0;
    float v2 = f[r];
    if (++r == K_SIZE) r = 0;
    float v3 = f[r];

    if (i0 + 3 < n) {
        *reinterpret_cast<float4*>(out + i0) = make_float4(v0, v1, v2, v3);
    } else {
        out[i0] = v0;
        if (i0 + 1 < n) out[i0 + 1] = v1;
        if (i0 + 2 < n) out[i0 + 2] = v2;
    }
}

extern "C" void kernel_launch(void* const* d_in, const int* in_sizes, int n_in,
                              void* d_out, int out_size, void* d_ws, size_t ws_size,
                              hipStream_t stream) {
    const float* in      = (const float*)d_in[0];
    const float* scale_p = (const float*)d_in[1];
    float* out = (float*)d_out;

    const int n = in_sizes[0];

    // Reference: missing = K - n; left = missing//2 + 2 (Python floor div).
    // For n=8191: missing=-8150 -> left=-4073 -> window = in[4073:4114].
    const int missing = K_SIZE - n;
    int fd = missing / 2;
    if ((missing % 2 != 0) && (missing < 0)) fd -= 1;  // Python floor division
    const int left = fd + 2;
    const int start = -left;

    const int block = 64;
    const int elems_per_block = block * 4;
    const int grid = (n + elems_per_block - 1) / elems_per_block;
    FlatDilation1D_kernel<<<grid, block, 0, stream>>>(in, scale_p, out, n, start);
}